// Round 1
// 5273.946 us; speedup vs baseline: 1.1705x; 1.1705x over previous
//
#include <hip/hip_runtime.h>
#include <stdint.h>

// ---------------------------------------------------------------------------
// Fused spiking-MLP forward: 20 timesteps, B=16384, 784 -> 400 -> 10.
//
// RNG: jax threefry, PARTITIONABLE semantics (verified absmax 0.0):
//   key_t = TF((0,42),(0,t)); per element e: bits = x0^x1 of TF(key_t,(0,e));
//   u = bitcast((bits>>9)|0x3f800000)-1.0f; xi = (x > u).
//
// V2 structure (vs 6173us baseline):
//  * TWO timesteps share ONE W1 tile sweep (dots are state-independent):
//    each LDS-read + f64-convert of wd[k] feeds 8 conditional-add streams
//    (4 samples x 2 steps) instead of 4 -> halves operand-prep VALU work
//    and halves staging sweeps + barriers.
//  * 512-thread blocks, wave = (sample-group sg, neuron-half kh). kh=0 owns
//    j = lane+64k (k<4), kh=1 owns j = 256+lane+64k. Keeps per-thread f64
//    state at mem1[4][4]+acc1[4][4] = 64 VGPR -> 4 waves/SIMD.
//  * xi bit-words hoisted to SGPR once per tile -> inner tests are pure
//    scalar (s_and + s_cbranch), no per-test VALU ops.
//  * Next W1 tile prefetched into registers right after the ds_write, so
//    global (L2) latency overlaps the ~2000-cycle compute phase instead of
//    sitting between the two barriers.
// Membrane state & dots stay fp64 (knife-edge spike thresholds). Summation
// order per timestep is unchanged -> numerics preserved.
// ---------------------------------------------------------------------------

#define BSZ    16384
#define INDIM  784
#define HID    400
#define ODIM   10
#define TSTEPS 20

#define TD   16           // d-tile size
#define NT   49           // 784/16 tiles
#define WTJ  512          // padded neuron rows in LDS tile (400 real)
#define XIW  26           // xi words per sample (784 bits -> 25, +1 pad)
#define SPW  14           // spike words per sample

__device__ __forceinline__ void tfr(uint32_t& x0, uint32_t& x1, int r) {
  x0 += x1;
  x1 = (x1 << r) | (x1 >> (32 - r));
  x1 ^= x0;
}

__device__ __forceinline__ uint2 tf2x32(uint32_t k0, uint32_t k1,
                                        uint32_t c0, uint32_t c1) {
  uint32_t k2 = k0 ^ k1 ^ 0x1BD11BDAu;
  uint32_t x0 = c0 + k0, x1 = c1 + k1;
  tfr(x0,x1,13); tfr(x0,x1,15); tfr(x0,x1,26); tfr(x0,x1,6);
  x0 += k1; x1 += k2 + 1u;
  tfr(x0,x1,17); tfr(x0,x1,29); tfr(x0,x1,16); tfr(x0,x1,24);
  x0 += k2; x1 += k0 + 2u;
  tfr(x0,x1,13); tfr(x0,x1,15); tfr(x0,x1,26); tfr(x0,x1,6);
  x0 += k0; x1 += k1 + 3u;
  tfr(x0,x1,17); tfr(x0,x1,29); tfr(x0,x1,16); tfr(x0,x1,24);
  x0 += k1; x1 += k2 + 4u;
  tfr(x0,x1,13); tfr(x0,x1,15); tfr(x0,x1,26); tfr(x0,x1,6);
  x0 += k2; x1 += k0 + 5u;
  return make_uint2(x0, x1);
}

__device__ __forceinline__ float bits_to_unif(uint32_t b) {
  return __uint_as_float((b >> 9) | 0x3f800000u) - 1.0f;
}

__global__ __launch_bounds__(512, 4)
void snn_fused(const float* __restrict__ x,  const float* __restrict__ W1,
               const float* __restrict__ b1, const float* __restrict__ W2,
               const float* __restrict__ b2, float* __restrict__ out) {
  __shared__ float    wt[TD * WTJ];        // 32768 B, layout [dt][j]
  __shared__ uint32_t xib[2][16][XIW];     // 3328 B  (xi bits for t0,t1)
  __shared__ uint32_t spk[16][SPW];        // 896 B

  const int tid  = threadIdx.x;            // 0..511
  const int g    = blockIdx.x;             // 0..1023
  const int wv   = tid >> 6;               // wave 0..7
  const int sg   = wv >> 1;                // sample group 0..3 (4 samples)
  const int kh   = wv & 1;                 // neuron half: j base 0 / 256
  const int lane = tid & 63;
  const int jb   = 256 * kh + lane;        // neuron j for k=0

  // zero the padded wt rows (j in [400,512)) ONCE; staging never touches them
  for (int i = tid; i < TD * WTJ; i += 512)
    if ((i & (WTJ - 1)) >= HID) wt[i] = 0.0f;

  // biases of owned neurons (j >= 400 are dummies, stay at 0 -> never fire)
  double bb[4];
#pragma unroll
  for (int k = 0; k < 4; ++k) {
    const int j = jb + 64 * k;
    bb[k] = (j < HID) ? (double)b1[j] : 0.0;
  }

  // persistent layer-1 state: samples 4sg+s, neurons j = jb + 64k
  double   mem1[4][4];                     // membrane (carried across steps)
  double   acc1[4][4];                     // dot accumulator for odd step
  uint32_t spv[4];                         // prev-step spike bits (bit k)
#pragma unroll
  for (int s = 0; s < 4; ++s) {
    spv[s] = 0u;
#pragma unroll
    for (int k = 0; k < 4; ++k) { mem1[s][k] = 0.0; acc1[s][k] = 0.0; }
  }

  // layer-2 ownership: tid<160 -> (sample ls, output lo)
  const int ls = tid / ODIM;
  const int lo = tid - ls * ODIM;
  double m2 = 0.0;
  int    s2 = 0, cnt2 = 0;
  const double b2r = (tid < 160) ? (double)b2[lo] : 0.0;

  auto layer2_step = [&]() {
    if (tid < 160) {
      double a2  = s2 ? 0.0 : m2 * 0.2;
      double dot = 0.0;
      for (int ww = 0; ww < 13; ++ww) {
        uint32_t bits = spk[ls][ww];
        if (ww == 12) bits &= 0xFFFFu;     // j in [384,400)
        const int jb2 = 32 * ww;
        while (bits) {
          const int bi = __ffs(bits) - 1;
          bits &= bits - 1u;
          dot += (double)W2[lo * HID + jb2 + bi];
        }
      }
      m2 = (a2 + dot) + b2r;
      s2 = (m2 > 0.5) ? 1 : 0;
      cnt2 += s2;
    }
  };

  // prefetch W1 tile 0 into registers (thread tid stages row j = tid)
  const bool stager = (tid < HID);
  float4 va = make_float4(0,0,0,0), vb = va, vc = va, vd = va;
  if (stager) {
    const float4* src = (const float4*)(W1 + tid * INDIM);
    va = src[0]; vb = src[1]; vc = src[2]; vd = src[3];
  }

  for (int tp = 0; tp < TSTEPS / 2; ++tp) {
    // ---- step keys for the pair ----
    const uint2 ka = tf2x32(0u, 42u, 0u, (uint32_t)(2 * tp));
    const uint2 kb = tf2x32(0u, 42u, 0u, (uint32_t)(2 * tp + 1));
    const uint32_t kx[2] = { ka.x, kb.x };
    const uint32_t ky[2] = { ka.y, kb.y };

    // ---- xi generation for BOTH steps; c-range split across kh pair ----
    const int cA = kh ? 7 : 0;
    const int cB = kh ? 13 : 7;
    for (int s = 0; s < 4; ++s) {
      const int q   = 4 * sg + s;
      const int row = g * 8 + (q & 7) + ((q >= 8) ? 8192 : 0);
      for (int c = cA; c < cB; ++c) {
        const int d = c * 64 + lane;
        const bool valid = (d < INDIM);
        float xv = 0.0f;
        if (valid) xv = x[row * INDIM + d];
        const uint32_t e = (uint32_t)row * (uint32_t)INDIM + (uint32_t)d;
#pragma unroll
        for (int tt = 0; tt < 2; ++tt) {
          int xb = 0;
          if (valid) {
            uint2 r = tf2x32(kx[tt], ky[tt], 0u, e);
            xb = xv > bits_to_unif(r.x ^ r.y);
          }
          unsigned long long m = __ballot(xb);
          if (lane == 0) {
            xib[tt][q][2*c]     = (uint32_t)m;
            xib[tt][q][2*c + 1] = (uint32_t)(m >> 32);
          }
        }
      }
    }

    // ---- decay + reset into t0 accumulator; zero t1 accumulator ----
#pragma unroll
    for (int s = 0; s < 4; ++s)
#pragma unroll
      for (int k = 0; k < 4; ++k) {
        mem1[s][k] = ((spv[s] >> k) & 1u) ? 0.0 : mem1[s][k] * 0.2;
        acc1[s][k] = 0.0;
      }

    // ---- ONE sweep over 49 W1 tiles feeds BOTH timesteps ----
    for (int td = 0; td < NT; ++td) {
      __syncthreads();                     // prev tile (or spk/xib) consumers done
      if (stager) {
        // commit prefetched tile td (transposed scatter, conflict-free)
        wt[ 0*WTJ + tid] = va.x;  wt[ 1*WTJ + tid] = va.y;
        wt[ 2*WTJ + tid] = va.z;  wt[ 3*WTJ + tid] = va.w;
        wt[ 4*WTJ + tid] = vb.x;  wt[ 5*WTJ + tid] = vb.y;
        wt[ 6*WTJ + tid] = vb.z;  wt[ 7*WTJ + tid] = vb.w;
        wt[ 8*WTJ + tid] = vc.x;  wt[ 9*WTJ + tid] = vc.y;
        wt[10*WTJ + tid] = vc.z;  wt[11*WTJ + tid] = vc.w;
        wt[12*WTJ + tid] = vd.x;  wt[13*WTJ + tid] = vd.y;
        wt[14*WTJ + tid] = vd.z;  wt[15*WTJ + tid] = vd.w;
        // issue next tile's loads NOW; they land during the compute phase
        const int tn = (td + 1 < NT) ? td + 1 : 0;   // wraps for next pair
        const float4* src = (const float4*)(W1 + tid * INDIM + tn * TD);
        va = src[0]; vb = src[1]; vc = src[2]; vd = src[3];
      }
      __syncthreads();                     // tile td ready

      // xi bit-words for this tile, hoisted to SGPR (wave-uniform)
      const int d0 = td * TD, wi = d0 >> 5, sh = d0 & 31;
      uint32_t bA[4], bB[4];
#pragma unroll
      for (int s = 0; s < 4; ++s) {
        bA[s] = (uint32_t)__builtin_amdgcn_readfirstlane(
                  (int)((xib[0][4*sg + s][wi] >> sh) & 0xFFFFu));
        bB[s] = (uint32_t)__builtin_amdgcn_readfirstlane(
                  (int)((xib[1][4*sg + s][wi] >> sh) & 0xFFFFu));
      }

#pragma unroll
      for (int dt = 0; dt < TD; ++dt) {
        double wd[4];
#pragma unroll
        for (int k = 0; k < 4; ++k)
          wd[k] = (double)wt[dt * WTJ + jb + 64 * k];
#pragma unroll
        for (int s = 0; s < 4; ++s) {
          if (bA[s] & (1u << dt)) {        // scalar test: s_and + s_cbranch
#pragma unroll
            for (int k = 0; k < 4; ++k) mem1[s][k] += wd[k];
          }
          if (bB[s] & (1u << dt)) {
#pragma unroll
            for (int k = 0; k < 4; ++k) acc1[s][k] += wd[k];
          }
        }
      }
    }

    // ---- finalize t0: + b1, threshold, pack spikes ----
#pragma unroll
    for (int s = 0; s < 4; ++s) {
      uint32_t m = 0u;
#pragma unroll
      for (int k = 0; k < 4; ++k) {
        mem1[s][k] += bb[k];
        if (mem1[s][k] > 0.5) m |= (1u << k);
      }
      spv[s] = m;
#pragma unroll
      for (int k = 0; k < 4; ++k) {
        unsigned long long bm = __ballot((m >> k) & 1u);
        const int w0 = 8 * kh + 2 * k;
        if (lane == 0 && w0 < SPW) {
          spk[4*sg + s][w0]     = (uint32_t)bm;
          spk[4*sg + s][w0 + 1] = (uint32_t)(bm >> 32);
        }
      }
    }
    __syncthreads();                       // spikes(t0) visible
    layer2_step();                         // t0
    __syncthreads();                       // spk consumed

    // ---- finalize t1: decay(t0 state) + acc1 + b1, threshold, pack ----
#pragma unroll
    for (int s = 0; s < 4; ++s) {
      uint32_t m = 0u;
#pragma unroll
      for (int k = 0; k < 4; ++k) {
        double v = ((spv[s] >> k) & 1u) ? 0.0 : mem1[s][k] * 0.2;
        v += acc1[s][k];
        v += bb[k];
        mem1[s][k] = v;
        if (v > 0.5) m |= (1u << k);
      }
      spv[s] = m;
#pragma unroll
      for (int k = 0; k < 4; ++k) {
        unsigned long long bm = __ballot((m >> k) & 1u);
        const int w0 = 8 * kh + 2 * k;
        if (lane == 0 && w0 < SPW) {
          spk[4*sg + s][w0]     = (uint32_t)bm;
          spk[4*sg + s][w0 + 1] = (uint32_t)(bm >> 32);
        }
      }
    }
    __syncthreads();                       // spikes(t1) visible
    layer2_step();                         // t1
    // next pair's tile-0 barrier protects spk/wt before overwrite
  }

  // ---- output: h2_sum / 20 ----
  if (tid < 160) {
    const int row = g * 8 + (ls & 7) + ((ls >= 8) ? 8192 : 0);
    out[row * ODIM + lo] = (float)((double)cnt2 / 20.0);
  }
}

extern "C" void kernel_launch(void* const* d_in, const int* in_sizes, int n_in,
                              void* d_out, int out_size, void* d_ws, size_t ws_size,
                              hipStream_t stream) {
  const float* x  = (const float*)d_in[0];
  const float* W1 = (const float*)d_in[1];
  const float* b1 = (const float*)d_in[2];
  const float* W2 = (const float*)d_in[3];
  const float* b2 = (const float*)d_in[4];
  // d_in[5] = time_window (int, ==20) — compile-time constant here.
  float* out = (float*)d_out;
  hipLaunchKernelGGL(snn_fused, dim3(1024), dim3(512), 0, stream,
                     x, W1, b1, W2, b2, out);
}